// Round 7
// baseline (5527.058 us; speedup 1.0000x reference)
//
#include <hip/hip_runtime.h>

#define B_ 128
#define T_ 256
#define I_ 512
#define H_ 1024

typedef _Float16 f16;
typedef _Float16 v8h __attribute__((ext_vector_type(8)));
typedef _Float16 v2h __attribute__((ext_vector_type(2)));
typedef float v16f __attribute__((ext_vector_type(16)));

__device__ __forceinline__ float fsigmoid(float x) { return 1.0f / (1.0f + __expf(-x)); }
__device__ __forceinline__ float ftanh(float x) { return 1.0f - 2.0f / (__expf(2.0f * x) + 1.0f); }

__device__ __forceinline__ void gl_lds16(const void* g, void* l) {
    __builtin_amdgcn_global_load_lds(
        (const __attribute__((address_space(1))) unsigned int*)g,
        (__attribute__((address_space(3))) unsigned int*)l, 16, 0, 0);
}
// SC0 only: bypass L1, served by own-XCD L2 (intra-XCD coherent)
__device__ __forceinline__ void gl_lds16_l2(const void* g, void* l) {
    __builtin_amdgcn_global_load_lds(
        (const __attribute__((address_space(1))) unsigned int*)g,
        (__attribute__((address_space(3))) unsigned int*)l, 16, 0, 1);
}
// device-coherent register load (LLC / coherence point)
__device__ __forceinline__ uint4 load16_dev(const void* p) {
    uint4 r;
    asm volatile("global_load_dwordx4 %0, %1, off sc0 sc1" : "=&v"(r) : "v"(p) : "memory");
    return r;
}

// ---------------- conversion kernels ----------------
__global__ void k_f32_to_f16(const float* __restrict__ in, f16* __restrict__ out, int n) {
    int i = blockIdx.x * blockDim.x + threadIdx.x;
    int st = gridDim.x * blockDim.x;
    for (; i < n; i += st) out[i] = (f16)in[i];
}
__global__ void k_bias_sum(const float* __restrict__ a, const float* __restrict__ b,
                           float* __restrict__ o, int n) {
    int i = blockIdx.x * blockDim.x + threadIdx.x;
    int st = gridDim.x * blockDim.x;
    for (; i < n; i += st) o[i] = a[i] + b[i];
}

// ---------------- persistent lockstep LSTM with per-XCD h staging ----------------
// 256 WGs x 512 threads, 1 WG/CU (LDS-forced) => exactly 32 WGs per XCD.
// Phase p: slot0 computes layer0[t=p] (p<256); slot1 computes layer1[t=p-1] (p>=1).
// Per phase: fresh panels h0[p-1], h1[p-2] staged ONCE per XCD into hstage[xcd]
// (device-coherent pull -> plain stores land in own L2); consumers read scratch
// with SC0 (L1-bypass, L2-hit). Need-mask stages only row-halves/panels consumed.
template <int SLOT>
__device__ void run_slot3(int mh, int tile, int gwidx, int rank, int xcd, int mask,
                          const f16* __restrict__ xh,
                          const f16* __restrict__ wi, const f16* __restrict__ wh,
                          const float* __restrict__ bs,
                          f16* __restrict__ h0, f16* __restrict__ h1,
                          f16* __restrict__ hstage,
                          float* __restrict__ out, int* flags, int* xflags, char* lds)
{
    constexpr int K0 = SLOT ? 1024 : 512;   // x/h boundary in combined K
    constexpr int KW = SLOT ? 512 : 384;    // per-kw-window width (K/4)
    constexpr int NR = KW / 64;
    constexpr int NKS = KW / 16;
    const size_t BH = (size_t)B_ * H_;

    const int tid = threadIdx.x;
    const int wave = tid >> 6;
    const int lane = tid & 63;
    const int l31 = lane & 31, khi = lane >> 5;
    const int nw = wave & 1, kw = wave >> 1;
    const int n0 = tile * 16;
    const int rbase = mh * 64;

    // ---- W fragments -> registers/AGPRs (once) ----
    const int gcl = nw * 32 + l31;
    const size_t gr = (size_t)(gcl >> 4) * H_ + n0 + (gcl & 15);
    v8h wfrag[NKS];
#pragma unroll
    for (int s = 0; s < NKS; ++s) {
        const int k = kw * KW + s * 16 + khi * 8;
        const f16* p = (k < K0) ? (wi + gr * K0 + k) : (wh + gr * H_ + (k - K0));
        wfrag[s] = *(const v8h*)p;
    }

    // ---- per-thread cell state + biases (2 cells) ----
    const int urow = tid >> 3;
    const int un = (tid & 7) * 2;
    const float2 bI = *(const float2*)(bs + 0 * H_ + n0 + un);
    const float2 bF = *(const float2*)(bs + 1 * H_ + n0 + un);
    const float2 bG = *(const float2*)(bs + 2 * H_ + n0 + un);
    const float2 bO = *(const float2*)(bs + 3 * H_ + n0 + un);
    float c0r = 0.f, c1r = 0.f;

    f16* hs = hstage + (size_t)xcd * 262144;      // [2][128][1024] f16 per XCD
    float* red = (float*)(lds + 65536);
    float* gf  = (float*)(lds + 114688);

    // stage assignment: chunk `rank` (16KB = 8 rows); chunks 0-15: h0, 16-31: h1
    const bool do_stage = (rank < 32) && (mask & (1 << (rank >> 3)));
    const size_t soff = ((size_t)rank * 16384 + (size_t)tid * 32) / 2;   // f16 elems

#pragma unroll 1
    for (int p = 0; p <= T_; ++p) {
        // ---- global wait: all 256 WGs completed phase p-1 (flag >= p+1) ----
        {
            const int tgt = p + 1;
            if (wave == 0) {
                for (;;) {
                    int a = __hip_atomic_load(flags + lane * 16, __ATOMIC_RELAXED, __HIP_MEMORY_SCOPE_AGENT);
                    int b = __hip_atomic_load(flags + (lane + 64) * 16, __ATOMIC_RELAXED, __HIP_MEMORY_SCOPE_AGENT);
                    int c = __hip_atomic_load(flags + (lane + 128) * 16, __ATOMIC_RELAXED, __HIP_MEMORY_SCOPE_AGENT);
                    int d = __hip_atomic_load(flags + (lane + 192) * 16, __ATOMIC_RELAXED, __HIP_MEMORY_SCOPE_AGENT);
                    if (__ballot(a >= tgt && b >= tgt && c >= tgt && d >= tgt) == ~0ULL) break;
                    __builtin_amdgcn_s_sleep(8);
                }
            }
            __syncthreads();
            __builtin_amdgcn_sched_barrier(0);
        }

        // ---- stage fresh h panels into own-XCD scratch ----
        if (do_stage) {
            const f16* src = (rank < 16)
                ? (h0 + (size_t)((p + 3) & 3) * BH + soff)
                : (h1 + (size_t)((p + 1) & 1) * BH + (soff - 131072));
            uint4 va = load16_dev(src);
            uint4 vb = load16_dev(src + 8);
            asm volatile("s_waitcnt vmcnt(0)" ::: "memory");
            *(uint4*)(hs + soff) = va;          // plain store -> own L2 (write-back)
            *(uint4*)(hs + soff + 8) = vb;
        }
        asm volatile("s_waitcnt vmcnt(0)" ::: "memory");
        __syncthreads();
        if (tid == 0 && rank < 32)
            __hip_atomic_store(xflags + (xcd * 64 + rank) * 16, p + 1, __ATOMIC_RELAXED, __HIP_MEMORY_SCOPE_AGENT);

        // ---- XCD stage barrier (32 ranks) ----
        if (wave == 0) {
            const int tgt = p + 1;
            for (;;) {
                int v = __hip_atomic_load(xflags + (xcd * 64 + lane) * 16, __ATOMIC_RELAXED, __HIP_MEMORY_SCOPE_AGENT);
                if (__ballot(lane >= 32 || v >= tgt) == ~0ULL) break;
                __builtin_amdgcn_s_sleep(1);
            }
        }
        __syncthreads();
        __builtin_amdgcn_sched_barrier(0);

        const bool active = SLOT ? (p >= 1) : (p < T_);
        if (active) {
            const int tau = SLOT ? p - 1 : p;
            const f16* srcA; size_t strA; const f16* srcB; f16* hout;
            if (SLOT == 0) {
                srcA = xh + (size_t)tau * I_;  strA = (size_t)T_ * I_;
                srcB = hs;                      // staged h0[p-1]
                hout = h0 + (size_t)(p & 3) * BH;
            } else {
                srcA = hs;  strA = (size_t)H_;  // staged h0[p-1]
                srcB = hs + 131072;             // staged h1[p-2]
                hout = h1 + (size_t)(p & 1) * BH;
            }

            v16f acc0 = {}, acc1 = {};

            auto issue = [&](int r) {
                const int kc = kw * KW + r * 64;
                const f16* base; size_t str; int koff; bool l2;
                if (kc < K0) { base = srcA; str = strA; koff = kc; l2 = (SLOT == 1); }
                else         { base = srcB; str = (size_t)H_; koff = kc - K0; l2 = true; }
                char* dbase = lds + (size_t)(kw * 2 + (r & 1)) * 8192 + nw * 4096;
                const int rw = lane >> 3;
                const int ss = (lane & 7) ^ rw;              // pre-swizzled source slot
#pragma unroll
                for (int i = 0; i < 4; ++i) {
                    const int rl = rbase + nw * 32 + i * 8 + rw;
                    const f16* gp = base + (size_t)rl * str + koff + ss * 8;
                    if (l2) gl_lds16_l2(gp, dbase + i * 1024);
                    else    gl_lds16(gp, dbase + i * 1024);
                }
            };

            issue(0);
#pragma unroll 1
            for (int r = 0; r < NR; ++r) {
                asm volatile("s_waitcnt vmcnt(0)" ::: "memory");
                __builtin_amdgcn_s_barrier();
                __builtin_amdgcn_sched_barrier(0);
                if (r + 1 < NR) issue(r + 1);
                const char* sb = lds + (size_t)(kw * 2 + (r & 1)) * 8192;
#pragma unroll
                for (int ks = 0; ks < 4; ++ks) {
                    const int qo = (((ks * 2 + khi) ^ (l31 & 7)) << 4);
                    const v8h a0 = *(const v8h*)(sb + l31 * 128 + qo);
                    const v8h a1 = *(const v8h*)(sb + (32 + l31) * 128 + qo);
                    __builtin_amdgcn_s_setprio(1);
                    acc0 = __builtin_amdgcn_mfma_f32_32x32x16_f16(a0, wfrag[r * 4 + ks], acc0, 0, 0, 0);
                    acc1 = __builtin_amdgcn_mfma_f32_32x32x16_f16(a1, wfrag[r * 4 + ks], acc1, 0, 0, 0);
                    __builtin_amdgcn_s_setprio(0);
                }
            }

            // ---- kw-partial reduction: 4 -> 2 -> 1 ----
            if (kw >= 2) {
                float* rg = red + ((kw - 2) * 2 + nw) * 2048;
#pragma unroll
                for (int j = 0; j < 16; ++j) {
                    rg[j * 64 + lane] = acc0[j];
                    rg[(16 + j) * 64 + lane] = acc1[j];
                }
            }
            __syncthreads();
            if (kw < 2) {
                const float* rg = red + (kw * 2 + nw) * 2048;
#pragma unroll
                for (int j = 0; j < 16; ++j) {
                    acc0[j] += rg[j * 64 + lane];
                    acc1[j] += rg[(16 + j) * 64 + lane];
                }
                if (kw == 1) {
                    float* r2 = red + 8192 + nw * 2048;
#pragma unroll
                    for (int j = 0; j < 16; ++j) {
                        r2[j * 64 + lane] = acc0[j];
                        r2[(16 + j) * 64 + lane] = acc1[j];
                    }
                }
            }
            __syncthreads();
            if (kw == 0) {
                const float* r2 = red + 8192 + nw * 2048;
#pragma unroll
                for (int j = 0; j < 16; ++j) {
                    const int row = (j & 3) + 8 * (j >> 2) + 4 * khi;
                    gf[row * 68 + nw * 32 + l31] = acc0[j] + r2[j * 64 + lane];
                    gf[(32 + row) * 68 + nw * 32 + l31] = acc1[j] + r2[(16 + j) * 64 + lane];
                }
            }
            __syncthreads();

            // ---- fused cell update: 2 cells/thread, c in registers ----
            {
                const float* g0 = gf + urow * 68 + un;
                const float xi0 = g0[0] + bI.x,  xi1 = g0[1] + bI.y;
                const float xf0 = g0[16] + bF.x, xf1 = g0[17] + bF.y;
                const float xg0 = g0[32] + bG.x, xg1 = g0[33] + bG.y;
                const float xo0 = g0[48] + bO.x, xo1 = g0[49] + bO.y;
                const float cn0 = fsigmoid(xf0) * c0r + fsigmoid(xi0) * ftanh(xg0);
                const float cn1 = fsigmoid(xf1) * c1r + fsigmoid(xi1) * ftanh(xg1);
                const float hn0 = fsigmoid(xo0) * ftanh(cn0);
                const float hn1 = fsigmoid(xo1) * ftanh(cn1);
                c0r = cn0; c1r = cn1;
                union { v2h h2; unsigned u; } cv;
                cv.h2[0] = (f16)hn0; cv.h2[1] = (f16)hn1;
                unsigned* hp = (unsigned*)(hout + (size_t)(rbase + urow) * H_ + n0 + un);
                asm volatile("global_store_dword %0, %1, off sc0 sc1" :: "v"(hp), "v"(cv.u) : "memory");
                if (SLOT == 1) {
                    float2 yv; yv.x = hn0; yv.y = hn1;
                    *(float2*)(out + ((size_t)(rbase + urow) * T_ + tau) * H_ + n0 + un) = yv;
                }
            }
        }

        // ---- arrive ----
        asm volatile("s_waitcnt vmcnt(0)" ::: "memory");
        __syncthreads();
        if (tid == 0)
            __hip_atomic_store(flags + gwidx * 16, p + 2, __ATOMIC_RELAXED, __HIP_MEMORY_SCOPE_AGENT);
    }
}

__global__ __launch_bounds__(512, 2) void lstm_persist3(
    const f16* __restrict__ xh,
    const f16* __restrict__ w0i, const f16* __restrict__ w0h,
    const f16* __restrict__ w1i, const f16* __restrict__ w1h,
    const float* __restrict__ bs0, const float* __restrict__ bs1,
    f16* __restrict__ h0, f16* __restrict__ h1, f16* __restrict__ hstage,
    float* __restrict__ out,
    int* flags, int* xflags, int* xcdcnt, int* xneed)
{
    __shared__ __align__(16) char lds[132608];
    const int bx = blockIdx.x;
    const int slot = bx & 1;
    const int mh = (bx >> 1) & 1;
    const int tile = bx >> 2;
    const int gwidx = slot * 128 + mh * 64 + tile;

    int xcd;
    asm("s_getreg_b32 %0, hwreg(HW_REG_XCC_ID)" : "=s"(xcd));
    xcd &= 7;

    int* shi = (int*)(lds + 132096);
    if (threadIdx.x == 0) {
        int r = __hip_atomic_fetch_add(xcdcnt + xcd, 1, __ATOMIC_RELAXED, __HIP_MEMORY_SCOPE_AGENT);
        const int bits = (slot == 0) ? (1 << mh) : ((1 << mh) | (1 << (2 + mh)));
        __hip_atomic_fetch_or(xneed + xcd, bits, __ATOMIC_RELAXED, __HIP_MEMORY_SCOPE_AGENT);
        shi[0] = r;
        __hip_atomic_store(flags + gwidx * 16, 1, __ATOMIC_RELAXED, __HIP_MEMORY_SCOPE_AGENT);  // init arrive
    }
    __syncthreads();
    const int rank = shi[0];

    // init barrier: all 256 WGs registered their needs
    if ((threadIdx.x >> 6) == 0) {
        const int lane = threadIdx.x & 63;
        for (;;) {
            int a = __hip_atomic_load(flags + lane * 16, __ATOMIC_RELAXED, __HIP_MEMORY_SCOPE_AGENT);
            int b = __hip_atomic_load(flags + (lane + 64) * 16, __ATOMIC_RELAXED, __HIP_MEMORY_SCOPE_AGENT);
            int c = __hip_atomic_load(flags + (lane + 128) * 16, __ATOMIC_RELAXED, __HIP_MEMORY_SCOPE_AGENT);
            int d = __hip_atomic_load(flags + (lane + 192) * 16, __ATOMIC_RELAXED, __HIP_MEMORY_SCOPE_AGENT);
            if (__ballot(a >= 1 && b >= 1 && c >= 1 && d >= 1) == ~0ULL) break;
            __builtin_amdgcn_s_sleep(4);
        }
    }
    __syncthreads();
    if (threadIdx.x == 0)
        shi[1] = __hip_atomic_load(xneed + xcd, __ATOMIC_RELAXED, __HIP_MEMORY_SCOPE_AGENT);
    __syncthreads();
    const int mask = shi[1];

    if (slot == 0)
        run_slot3<0>(mh, tile, gwidx, rank, xcd, mask, xh, w0i, w0h, bs0, h0, h1, hstage, out, flags, xflags, lds);
    else
        run_slot3<1>(mh, tile, gwidx, rank, xcd, mask, xh, w1i, w1h, bs1, h0, h1, hstage, out, flags, xflags, lds);
}

// ---------------- fp32 fallback (round-1 verified) ----------------
#define BM 64
#define NT 8

__global__ __launch_bounds__(256) void lstm_step(
    const float* __restrict__ A1, long a1_stride, int K1,
    const float* __restrict__ hprev,
    const float* __restrict__ Wih, const float* __restrict__ Whh,
    const float* __restrict__ bih, const float* __restrict__ bhh,
    float* __restrict__ cbuf, float* __restrict__ hout,
    float* yout, long y_stride)
{
    __shared__ float As[32][66];
    __shared__ float Ws[32][36];
    const int tid = threadIdx.x;
    const int n0 = blockIdx.x * NT;
    const int b0 = blockIdx.y * BM;
    const int tb = tid >> 3;
    const int tc = tid & 7;
    const int lr = tid >> 3;
    const int lk = tid & 7;
    const long wj = (long)(lr >> 3) * H_ + n0 + (lr & 7);
    float acc[2][4] = {{0.f, 0.f, 0.f, 0.f}, {0.f, 0.f, 0.f, 0.f}};
#pragma unroll 1
    for (int ph = 0; ph < 2; ++ph) {
        const float* Ap = (ph == 0) ? A1 : hprev;
        const long as = (ph == 0) ? a1_stride : (long)H_;
        const float* W = (ph == 0) ? Wih : Whh;
        const int K = (ph == 0) ? K1 : H_;
        const float* arow0 = Ap + (long)(b0 + lr) * as + 4 * lk;
        const float* arow1 = Ap + (long)(b0 + lr + 32) * as + 4 * lk;
        const float* wrow = W + wj * K + 4 * lk;
        float4 ra0 = *(const float4*)(arow0);
        float4 ra1 = *(const float4*)(arow1);
        float4 rw = *(const float4*)(wrow);
        for (int k0 = 0; k0 < K; k0 += 32) {
            __syncthreads();
            {
                const int kk = 4 * lk;
                As[kk + 0][lr] = ra0.x; As[kk + 1][lr] = ra0.y;
                As[kk + 2][lr] = ra0.z; As[kk + 3][lr] = ra0.w;
                As[kk + 0][lr + 32] = ra1.x; As[kk + 1][lr + 32] = ra1.y;
                As[kk + 2][lr + 32] = ra1.z; As[kk + 3][lr + 32] = ra1.w;
                Ws[kk + 0][lr] = rw.x; Ws[kk + 1][lr] = rw.y;
                Ws[kk + 2][lr] = rw.z; Ws[kk + 3][lr] = rw.w;
            }
            __syncthreads();
            const int kn = k0 + 32;
            if (kn < K) {
                ra0 = *(const float4*)(arow0 + kn);
                ra1 = *(const float4*)(arow1 + kn);
                rw = *(const float4*)(wrow + kn);
            }
#pragma unroll
            for (int k = 0; k < 32; ++k) {
                float2 a = *(const float2*)&As[k][2 * tb];
                float4 w = *(const float4*)&Ws[k][4 * tc];
                acc[0][0] = fmaf(a.x, w.x, acc[0][0]);
                acc[0][1] = fmaf(a.x, w.y, acc[0][1]);
                acc[0][2] = fmaf(a.x, w.z, acc[0][2]);
                acc[0][3] = fmaf(a.x, w.w, acc[0][3]);
                acc[1][0] = fmaf(a.y, w.x, acc[1][0]);
                acc[1][1] = fmaf(a.y, w.y, acc[1][1]);
                acc[1][2] = fmaf(a.y, w.z, acc[1][2]);
                acc[1][3] = fmaf(a.y, w.w, acc[1][3]);
            }
        }
    }
    __syncthreads();
    float* gsf = &As[0][0];
#pragma unroll
    for (int bi = 0; bi < 2; ++bi)
#pragma unroll
        for (int ci = 0; ci < 4; ++ci)
            gsf[(2 * tb + bi) * 33 + 4 * tc + ci] = acc[bi][ci];
    __syncthreads();
    const int dn = tid & 7;
    const int bq = tid >> 3;
    const int n = n0 + dn;
#pragma unroll
    for (int s = 0; s < 2; ++s) {
        const int b = bq + 32 * s;
        float xi = gsf[b * 33 + dn] + bih[n] + bhh[n];
        float xf = gsf[b * 33 + 8 + dn] + bih[H_ + n] + bhh[H_ + n];
        float xg = gsf[b * 33 + 16 + dn] + bih[2 * H_ + n] + bhh[2 * H_ + n];
        float xo = gsf[b * 33 + 24 + dn] + bih[3 * H_ + n] + bhh[3 * H_ + n];
        const long idx = (long)(b0 + b) * H_ + n;
        const float c_old = cbuf[idx];
        const float cn = fsigmoid(xf) * c_old + fsigmoid(xi) * ftanh(xg);
        const float hn = fsigmoid(xo) * ftanh(cn);
        cbuf[idx] = cn;
        hout[idx] = hn;
        if (yout) yout[(long)(b0 + b) * y_stride + n] = hn;
    }
}

extern "C" void kernel_launch(void* const* d_in, const int* in_sizes, int n_in,
                              void* d_out, int out_size, void* d_ws, size_t ws_size,
                              hipStream_t stream) {
    const float* x = (const float*)d_in[0];
    const float* Wih0 = (const float*)d_in[1];
    const float* Whh0 = (const float*)d_in[2];
    const float* bih0 = (const float*)d_in[3];
    const float* bhh0 = (const float*)d_in[4];
    const float* Wih1 = (const float*)d_in[5];
    const float* Whh1 = (const float*)d_in[6];
    const float* bih1 = (const float*)d_in[7];
    const float* bhh1 = (const float*)d_in[8];
    float* out = (float*)d_out;

    const size_t BH = (size_t)B_ * H_;
    const size_t NX = (size_t)B_ * T_ * I_;
    const size_t NW0I = (size_t)4 * H_ * I_;
    const size_t NWH = (size_t)4 * H_ * H_;

    const size_t off_xh = 0;
    const size_t off_w0i = off_xh + NX * 2;
    const size_t off_w0h = off_w0i + NW0I * 2;
    const size_t off_w1i = off_w0h + NWH * 2;
    const size_t off_w1h = off_w1i + NWH * 2;
    const size_t off_bs0 = off_w1h + NWH * 2;
    const size_t off_bs1 = off_bs0 + 4 * H_ * 4;
    const size_t off_h0 = off_bs1 + 4 * H_ * 4;            // 4 buffers
    const size_t off_h1 = off_h0 + 4 * BH * 2;             // 2 buffers
    const size_t off_flags = off_h1 + 2 * BH * 2;          // 256 x 16 ints
    const size_t off_xflags = off_flags + 256 * 16 * 4;    // 8 x 64 x 16 ints
    const size_t off_xcnt = off_xflags + 512 * 16 * 4;     // 8 ints (padded 256B)
    const size_t off_xneed = off_xcnt + 256;               // 8 ints (padded 256B)
    const size_t off_hstage = off_xneed + 256;             // 8 XCD x 512KB
    const size_t REQ = off_hstage + (size_t)8 * 262144 * 2;

    char* ws = (char*)d_ws;

    if (ws_size >= REQ) {
        f16* xh = (f16*)(ws + off_xh);
        f16* w0i = (f16*)(ws + off_w0i);
        f16* w0h = (f16*)(ws + off_w0h);
        f16* w1i = (f16*)(ws + off_w1i);
        f16* w1h = (f16*)(ws + off_w1h);
        float* bs0 = (float*)(ws + off_bs0);
        float* bs1 = (float*)(ws + off_bs1);
        f16* h0 = (f16*)(ws + off_h0);
        f16* h1 = (f16*)(ws + off_h1);
        int* flags = (int*)(ws + off_flags);
        int* xflags = (int*)(ws + off_xflags);
        int* xcdcnt = (int*)(ws + off_xcnt);
        int* xneed = (int*)(ws + off_xneed);
        f16* hstage = (f16*)(ws + off_hstage);

        // zero h0, h1, flags, xflags, counters, hstage — contiguous tail
        hipMemsetAsync(ws + off_h0, 0, REQ - off_h0, stream);

        dim3 cb(256);
        k_f32_to_f16<<<2048, cb, 0, stream>>>(x, xh, (int)NX);
        k_f32_to_f16<<<2048, cb, 0, stream>>>(Wih0, w0i, (int)NW0I);
        k_f32_to_f16<<<2048, cb, 0, stream>>>(Whh0, w0h, (int)NWH);
        k_f32_to_f16<<<2048, cb, 0, stream>>>(Wih1, w1i, (int)NWH);
        k_f32_to_f16<<<2048, cb, 0, stream>>>(Whh1, w1h, (int)NWH);
        k_bias_sum<<<16, cb, 0, stream>>>(bih0, bhh0, bs0, 4 * H_);
        k_bias_sum<<<16, cb, 0, stream>>>(bih1, bhh1, bs1, 4 * H_);

        lstm_persist3<<<256, 512, 0, stream>>>(xh, w0i, w0h, w1i, w1h, bs0, bs1,
                                               h0, h1, hstage, out,
                                               flags, xflags, xcdcnt, xneed);
        return;
    }

    // ---------- fp32 fallback ----------
    float* fws = (float*)d_ws;
    float* h0a = fws;
    float* h0b = fws + BH;
    float* c0 = fws + 2 * BH;
    float* h1a = fws + 3 * BH;
    float* h1b = fws + 4 * BH;
    float* c1 = fws + 5 * BH;
    hipMemsetAsync(d_ws, 0, 6 * BH * sizeof(float), stream);

    dim3 grid(H_ / NT, B_ / BM);
    dim3 block(256);
    for (int t = 0; t < T_; ++t) {
        float* h0in = (t & 1) ? h0b : h0a;
        float* h0out = (t & 1) ? h0a : h0b;
        float* h1in = (t & 1) ? h1b : h1a;
        float* h1out = (t & 1) ? h1a : h1b;
        lstm_step<<<grid, block, 0, stream>>>(
            x + (size_t)t * I_, (long)T_ * I_, I_,
            h0in, Wih0, Whh0, bih0, bhh0, c0, h0out, nullptr, 0);
        lstm_step<<<grid, block, 0, stream>>>(
            h0out, (long)H_, H_,
            h1in, Wih1, Whh1, bih1, bhh1, c1, h1out,
            out + (size_t)t * H_, (long)T_ * H_);
    }
}

// Round 8
// 2402.949 us; speedup vs baseline: 2.3001x; 2.3001x over previous
//
#include <hip/hip_runtime.h>

#define B_ 128
#define T_ 256
#define I_ 512
#define H_ 1024

typedef _Float16 f16;
typedef _Float16 v8h __attribute__((ext_vector_type(8)));
typedef _Float16 v2h __attribute__((ext_vector_type(2)));
typedef float v16f __attribute__((ext_vector_type(16)));

__device__ __forceinline__ float fsigmoid(float x) { return 1.0f / (1.0f + __expf(-x)); }
__device__ __forceinline__ float ftanh(float x) { return 1.0f - 2.0f / (__expf(2.0f * x) + 1.0f); }

__device__ __forceinline__ void gl_lds16(const void* g, void* l) {
    __builtin_amdgcn_global_load_lds(
        (const __attribute__((address_space(1))) unsigned int*)g,
        (__attribute__((address_space(3))) unsigned int*)l, 16, 0, 0);
}
// device-coherent (SC0|SC1): read the coherence point (fresh h)
__device__ __forceinline__ void gl_lds16_coh(const void* g, void* l) {
    __builtin_amdgcn_global_load_lds(
        (const __attribute__((address_space(1))) unsigned int*)g,
        (__attribute__((address_space(3))) unsigned int*)l, 16, 0, 17);
}
// 4 coherent flag loads in one block (single vmcnt drain)
__device__ __forceinline__ void poll4(const int* p0, const int* p1, const int* p2, const int* p3,
                                      int& a, int& b, int& c, int& d) {
    asm volatile("global_load_dword %0, %4, off sc0 sc1\n\t"
                 "global_load_dword %1, %5, off sc0 sc1\n\t"
                 "global_load_dword %2, %6, off sc0 sc1\n\t"
                 "global_load_dword %3, %7, off sc0 sc1\n\t"
                 "s_waitcnt vmcnt(0)"
                 : "=&v"(a), "=&v"(b), "=&v"(c), "=&v"(d)
                 : "v"(p0), "v"(p1), "v"(p2), "v"(p3)
                 : "memory");
}

// ---------------- conversion kernels ----------------
__global__ void k_f32_to_f16(const float* __restrict__ in, f16* __restrict__ out, int n) {
    int i = blockIdx.x * blockDim.x + threadIdx.x;
    int st = gridDim.x * blockDim.x;
    for (; i < n; i += st) out[i] = (f16)in[i];
}
__global__ void k_bias_sum(const float* __restrict__ a, const float* __restrict__ b,
                           float* __restrict__ o, int n) {
    int i = blockIdx.x * blockDim.x + threadIdx.x;
    int st = gridDim.x * blockDim.x;
    for (; i < n; i += st) o[i] = a[i] + b[i];
}

// ---------------- persistent 2-pipeline LSTM (slack protocol, deep pipeline) ----------------
// 256 WGs x 512 threads, 1 WG/CU (LDS 128KB). bx = tile*4 + mh*2 + slot.
// slot0 phase p: layer0[t=p] (p<256); slot1 phase p: layer1[t=p-1] (p>=1).
// h0 x4 buffers (slot0 may lead slot1 by 2 phases); h1 x2.
// Waits: slot0 {own>=p, oth>=p-2}; slot1 {own>=p, oth>=p}. Flag = completed-phase+1.
// Transport: h stores sc0|sc1 write-through; h DMA reads sc0|sc1; x plain cached.
// K-loop: 4 LDS bufs per kw-window, depth-3 issuance, counted vmcnt (8/4/0).
template <int SLOT>
__device__ void run_slot4(int mh, int tile, int widx128,
                          const f16* __restrict__ xh,
                          const f16* __restrict__ wi, const f16* __restrict__ wh,
                          const float* __restrict__ bs,
                          f16* __restrict__ h0, f16* __restrict__ h1,
                          float* __restrict__ out, int* flags, char* lds)
{
    constexpr int K0 = SLOT ? 1024 : 512;   // x/h boundary of combined K
    constexpr int KW = SLOT ? 512 : 384;    // per-kw-window width (K/4)
    constexpr int NR = KW / 64;             // 64-k rounds per window (6 or 8)
    constexpr int NKS = KW / 16;
    const size_t BH = (size_t)B_ * H_;

    const int tid = threadIdx.x;
    const int wave = tid >> 6;
    const int lane = tid & 63;
    const int l31 = lane & 31, khi = lane >> 5;
    const int nw = wave & 1, kw = wave >> 1;
    const int n0 = tile * 16;
    const int rbase = mh * 64;

    // ---- W fragments -> registers (once) ----
    const int gcl = nw * 32 + l31;
    const size_t gr = (size_t)(gcl >> 4) * H_ + n0 + (gcl & 15);
    v8h wfrag[NKS];
#pragma unroll
    for (int s = 0; s < NKS; ++s) {
        const int k = kw * KW + s * 16 + khi * 8;
        const f16* p = (k < K0) ? (wi + gr * K0 + k) : (wh + gr * H_ + (k - K0));
        wfrag[s] = *(const v8h*)p;
    }

    // ---- per-thread cell state + biases (2 cells) ----
    const int urow = tid >> 3;
    const int un = (tid & 7) * 2;
    const float2 bI = *(const float2*)(bs + 0 * H_ + n0 + un);
    const float2 bF = *(const float2*)(bs + 1 * H_ + n0 + un);
    const float2 bG = *(const float2*)(bs + 2 * H_ + n0 + un);
    const float2 bO = *(const float2*)(bs + 3 * H_ + n0 + un);
    float c0r = 0.f, c1r = 0.f;

    int* f_own = flags + SLOT * 512;         // 128 flags x 16B stride
    int* f_oth = flags + (1 - SLOT) * 512;

    // LDS overlay (post-K-loop): red1 [0,32K), red2 [32K,48K), gf [48K,~66K)
    float* red = (float*)lds;
    float* r2b = (float*)(lds + 32768);
    float* gf  = (float*)(lds + 49152);

    const int rw_ = lane >> 3;
    const int ss_ = (lane & 7) ^ rw_;        // pre-swizzled source 16B slot

#pragma unroll 1
    for (int p = 0; p <= T_; ++p) {
        const bool active = SLOT ? (p >= 1) : (p < T_);
        const int tau = SLOT ? p - 1 : p;

        const f16* srcA = nullptr; size_t strA = 0; const f16* srcB = nullptr; f16* hout = nullptr;
        if (active) {
            if (SLOT == 0) {
                srcA = xh + (size_t)tau * I_;  strA = (size_t)T_ * I_;
                srcB = h0 + (size_t)((p + 3) & 3) * BH;     // h0[p-1]
                hout = h0 + (size_t)(p & 3) * BH;           // h0[p]
            } else {
                srcA = h0 + (size_t)((p + 3) & 3) * BH;  strA = H_;   // h0[p-1]
                srcB = h1 + (size_t)((p + 1) & 1) * BH;               // h1[p-2]
                hout = h1 + (size_t)(p & 1) * BH;                     // h1[p-1]
            }
        }

        auto issue = [&](int r) {
            const int kc = kw * KW + r * 64;
            const f16* base; size_t str; int koff; bool coh;
            if (kc < K0) { base = srcA; str = strA; koff = kc; coh = (SLOT == 1); }
            else         { base = srcB; str = (size_t)H_; koff = kc - K0; coh = true; }
            char* dbase = lds + kw * 32768 + (r & 3) * 8192 + nw * 4096;
#pragma unroll
            for (int i = 0; i < 4; ++i) {
                const int rl = rbase + nw * 32 + i * 8 + rw_;
                const f16* gp = base + (size_t)rl * str + koff + ss_ * 8;
                if (coh) gl_lds16_coh(gp, dbase + i * 1024);
                else     gl_lds16(gp, dbase + i * 1024);
            }
        };

        // ---- pre-wait prefetch: x-only rounds (no dependency) ----
        unsigned premask = 0;
        if (active && SLOT == 0) {
#pragma unroll
            for (int r = 0; r < 3; ++r)
                if (kw * KW + r * 64 + 64 <= K0) { issue(r); premask |= 1u << r; }
        }

        // ---- wait (wave0 polls; one 4-load block per iteration) ----
        {
            const int t_own = p;
            const int t_oth = SLOT ? p : (p >= 2 ? p - 2 : 0);
            if (wave == 0) {
                const int* o0 = f_own + lane * 4;
                const int* o1 = f_own + (lane + 64) * 4;
                const int* q0 = f_oth + lane * 4;
                const int* q1 = f_oth + (lane + 64) * 4;
                for (;;) {
                    int a, b, c, d;
                    poll4(o0, o1, q0, q1, a, b, c, d);
                    if (__ballot(a >= t_own && b >= t_own && c >= t_oth && d >= t_oth) == ~0ULL) break;
                    __builtin_amdgcn_s_sleep(1);
                }
            }
            __syncthreads();
            __builtin_amdgcn_sched_barrier(0);
        }

        if (active) {
            // ---- remaining prologue ----
#pragma unroll
            for (int r = 0; r < 3; ++r)
                if (!(premask & (1u << r))) issue(r);

            v16f acc0 = {}, acc1 = {};

            // ---- K-loop: depth-3, counted vmcnt ----
#pragma unroll
            for (int r = 0; r < NR; ++r) {
                if (r < NR - 2)       asm volatile("s_waitcnt vmcnt(8)" ::: "memory");
                else if (r == NR - 2) asm volatile("s_waitcnt vmcnt(4)" ::: "memory");
                else                  asm volatile("s_waitcnt vmcnt(0)" ::: "memory");
                __builtin_amdgcn_s_barrier();
                __builtin_amdgcn_sched_barrier(0);
                if (r + 3 < NR) issue(r + 3);
                const char* sb = lds + kw * 32768 + (r & 3) * 8192;
#pragma unroll
                for (int ks = 0; ks < 4; ++ks) {
                    const int qo = (((ks * 2 + khi) ^ (l31 & 7)) << 4);
                    const v8h a0 = *(const v8h*)(sb + l31 * 128 + qo);
                    const v8h a1 = *(const v8h*)(sb + (32 + l31) * 128 + qo);
                    __builtin_amdgcn_s_setprio(1);
                    acc0 = __builtin_amdgcn_mfma_f32_32x32x16_f16(a0, wfrag[r * 4 + ks], acc0, 0, 0, 0);
                    acc1 = __builtin_amdgcn_mfma_f32_32x32x16_f16(a1, wfrag[r * 4 + ks], acc1, 0, 0, 0);
                    __builtin_amdgcn_s_setprio(0);
                }
            }
            __syncthreads();   // buffers free before red/gf overlay

            // ---- kw-partial reduction: 4 -> 2 -> 1 (overlaid LDS) ----
            if (kw >= 2) {
                float* rg = red + ((kw - 2) * 2 + nw) * 2048;
#pragma unroll
                for (int j = 0; j < 16; ++j) {
                    rg[j * 64 + lane] = acc0[j];
                    rg[(16 + j) * 64 + lane] = acc1[j];
                }
            }
            __syncthreads();
            if (kw < 2) {
                const float* rg = red + (kw * 2 + nw) * 2048;
#pragma unroll
                for (int j = 0; j < 16; ++j) {
                    acc0[j] += rg[j * 64 + lane];
                    acc1[j] += rg[(16 + j) * 64 + lane];
                }
                if (kw == 1) {
                    float* rr = r2b + nw * 2048;
#pragma unroll
                    for (int j = 0; j < 16; ++j) {
                        rr[j * 64 + lane] = acc0[j];
                        rr[(16 + j) * 64 + lane] = acc1[j];
                    }
                }
            }
            __syncthreads();
            if (kw == 0) {
                const float* rr = r2b + nw * 2048;
#pragma unroll
                for (int j = 0; j < 16; ++j) {
                    const int row = (j & 3) + 8 * (j >> 2) + 4 * khi;
                    gf[row * 68 + nw * 32 + l31] = acc0[j] + rr[j * 64 + lane];
                    gf[(32 + row) * 68 + nw * 32 + l31] = acc1[j] + rr[(16 + j) * 64 + lane];
                }
            }
            __syncthreads();

            // ---- fused cell update: 2 cells/thread, c in registers ----
            {
                const float* g0 = gf + urow * 68 + un;
                const float xi0 = g0[0] + bI.x,  xi1 = g0[1] + bI.y;
                const float xf0 = g0[16] + bF.x, xf1 = g0[17] + bF.y;
                const float xg0 = g0[32] + bG.x, xg1 = g0[33] + bG.y;
                const float xo0 = g0[48] + bO.x, xo1 = g0[49] + bO.y;
                const float cn0 = fsigmoid(xf0) * c0r + fsigmoid(xi0) * ftanh(xg0);
                const float cn1 = fsigmoid(xf1) * c1r + fsigmoid(xi1) * ftanh(xg1);
                const float hn0 = fsigmoid(xo0) * ftanh(cn0);
                const float hn1 = fsigmoid(xo1) * ftanh(cn1);
                c0r = cn0; c1r = cn1;
                union { v2h h2; unsigned u; } cv;
                cv.h2[0] = (f16)hn0; cv.h2[1] = (f16)hn1;
                unsigned* hp = (unsigned*)(hout + (size_t)(rbase + urow) * H_ + n0 + un);
                asm volatile("global_store_dword %0, %1, off sc0 sc1" :: "v"(hp), "v"(cv.u) : "memory");
                if (SLOT == 1) {
                    float2 yv; yv.x = hn0; yv.y = hn1;
                    *(float2*)(out + ((size_t)(rbase + urow) * T_ + tau) * H_ + n0 + un) = yv;
                }
            }
        }

        // ---- arrive: drain stores, join, publish flag ----
        asm volatile("s_waitcnt vmcnt(0)" ::: "memory");
        __syncthreads();
        if (tid == 0) {
            int v = p + 1;
            int* fp = f_own + widx128 * 4;
            asm volatile("global_store_dword %0, %1, off sc0 sc1" :: "v"(fp), "v"(v) : "memory");
        }
    }
}

__global__ __launch_bounds__(512, 2) void lstm_persist4(
    const f16* __restrict__ xh,
    const f16* __restrict__ w0i, const f16* __restrict__ w0h,
    const f16* __restrict__ w1i, const f16* __restrict__ w1h,
    const float* __restrict__ bs0, const float* __restrict__ bs1,
    f16* __restrict__ h0, f16* __restrict__ h1, float* __restrict__ out,
    int* flags)
{
    __shared__ __align__(16) char lds[131072];
    const int bx = blockIdx.x;
    const int slot = bx & 1;
    const int mh = (bx >> 1) & 1;
    const int tile = bx >> 2;
    const int widx128 = mh * 64 + tile;
    if (slot == 0)
        run_slot4<0>(mh, tile, widx128, xh, w0i, w0h, bs0, h0, h1, out, flags, lds);
    else
        run_slot4<1>(mh, tile, widx128, xh, w1i, w1h, bs1, h0, h1, out, flags, lds);
}

// ---------------- fp32 fallback (round-1 verified) ----------------
#define BM 64
#define NT 8

__global__ __launch_bounds__(256) void lstm_step(
    const float* __restrict__ A1, long a1_stride, int K1,
    const float* __restrict__ hprev,
    const float* __restrict__ Wih, const float* __restrict__ Whh,
    const float* __restrict__ bih, const float* __restrict__ bhh,
    float* __restrict__ cbuf, float* __restrict__ hout,
    float* yout, long y_stride)
{
    __shared__ float As[32][66];
    __shared__ float Ws[32][36];
    const int tid = threadIdx.x;
    const int n0 = blockIdx.x * NT;
    const int b0 = blockIdx.y * BM;
    const int tb = tid >> 3;
    const int tc = tid & 7;
    const int lr = tid >> 3;
    const int lk = tid & 7;
    const long wj = (long)(lr >> 3) * H_ + n0 + (lr & 7);
    float acc[2][4] = {{0.f, 0.f, 0.f, 0.f}, {0.f, 0.f, 0.f, 0.f}};
#pragma unroll 1
    for (int ph = 0; ph < 2; ++ph) {
        const float* Ap = (ph == 0) ? A1 : hprev;
        const long as = (ph == 0) ? a1_stride : (long)H_;
        const float* W = (ph == 0) ? Wih : Whh;
        const int K = (ph == 0) ? K1 : H_;
        const float* arow0 = Ap + (long)(b0 + lr) * as + 4 * lk;
        const float* arow1 = Ap + (long)(b0 + lr + 32) * as + 4 * lk;
        const float* wrow = W + wj * K + 4 * lk;
        float4 ra0 = *(const float4*)(arow0);
        float4 ra1 = *(const float4*)(arow1);
        float4 rw = *(const float4*)(wrow);
        for (int k0 = 0; k0 < K; k0 += 32) {
            __syncthreads();
            {
                const int kk = 4 * lk;
                As[kk + 0][lr] = ra0.x; As[kk + 1][lr] = ra0.y;
                As[kk + 2][lr] = ra0.z; As[kk + 3][lr] = ra0.w;
                As[kk + 0][lr + 32] = ra1.x; As[kk + 1][lr + 32] = ra1.y;
                As[kk + 2][lr + 32] = ra1.z; As[kk + 3][lr + 32] = ra1.w;
                Ws[kk + 0][lr] = rw.x; Ws[kk + 1][lr] = rw.y;
                Ws[kk + 2][lr] = rw.z; Ws[kk + 3][lr] = rw.w;
            }
            __syncthreads();
            const int kn = k0 + 32;
            if (kn < K) {
                ra0 = *(const float4*)(arow0 + kn);
                ra1 = *(const float4*)(arow1 + kn);
                rw = *(const float4*)(wrow + kn);
            }
#pragma unroll
            for (int k = 0; k < 32; ++k) {
                float2 a = *(const float2*)&As[k][2 * tb];
                float4 w = *(const float4*)&Ws[k][4 * tc];
                acc[0][0] = fmaf(a.x, w.x, acc[0][0]);
                acc[0][1] = fmaf(a.x, w.y, acc[0][1]);
                acc[0][2] = fmaf(a.x, w.z, acc[0][2]);
                acc[0][3] = fmaf(a.x, w.w, acc[0][3]);
                acc[1][0] = fmaf(a.y, w.x, acc[1][0]);
                acc[1][1] = fmaf(a.y, w.y, acc[1][1]);
                acc[1][2] = fmaf(a.y, w.z, acc[1][2]);
                acc[1][3] = fmaf(a.y, w.w, acc[1][3]);
            }
        }
    }
    __syncthreads();
    float* gsf = &As[0][0];
#pragma unroll
    for (int bi = 0; bi < 2; ++bi)
#pragma unroll
        for (int ci = 0; ci < 4; ++ci)
            gsf[(2 * tb + bi) * 33 + 4 * tc + ci] = acc[bi][ci];
    __syncthreads();
    const int dn = tid & 7;
    const int bq = tid >> 3;
    const int n = n0 + dn;
#pragma unroll
    for (int s = 0; s < 2; ++s) {
        const int b = bq + 32 * s;
        float xi = gsf[b * 33 + dn] + bih[n] + bhh[n];
        float xf = gsf[b * 33 + 8 + dn] + bih[H_ + n] + bhh[H_ + n];
        float xg = gsf[b * 33 + 16 + dn] + bih[2 * H_ + n] + bhh[2 * H_ + n];
        float xo = gsf[b * 33 + 24 + dn] + bih[3 * H_ + n] + bhh[3 * H_ + n];
        const long idx = (long)(b0 + b) * H_ + n;
        const float c_old = cbuf[idx];
        const float cn = fsigmoid(xf) * c_old + fsigmoid(xi) * ftanh(xg);
        const float hn = fsigmoid(xo) * ftanh(cn);
        cbuf[idx] = cn;
        hout[idx] = hn;
        if (yout) yout[(long)(b0 + b) * y_stride + n] = hn;
    }
}

extern "C" void kernel_launch(void* const* d_in, const int* in_sizes, int n_in,
                              void* d_out, int out_size, void* d_ws, size_t ws_size,
                              hipStream_t stream) {
    const float* x = (const float*)d_in[0];
    const float* Wih0 = (const float*)d_in[1];
    const float* Whh0 = (const float*)d_in[2];
    const float* bih0 = (const float*)d_in[3];
    const float* bhh0 = (const float*)d_in[4];
    const float* Wih1 = (const float*)d_in[5];
    const float* Whh1 = (const float*)d_in[6];
    const float* bih1 = (const float*)d_in[7];
    const float* bhh1 = (const float*)d_in[8];
    float* out = (float*)d_out;

    const size_t BH = (size_t)B_ * H_;
    const size_t NX = (size_t)B_ * T_ * I_;
    const size_t NW0I = (size_t)4 * H_ * I_;
    const size_t NWH = (size_t)4 * H_ * H_;

    const size_t off_xh = 0;
    const size_t off_w0i = off_xh + NX * 2;
    const size_t off_w0h = off_w0i + NW0I * 2;
    const size_t off_w1i = off_w0h + NWH * 2;
    const size_t off_w1h = off_w1i + NWH * 2;
    const size_t off_bs0 = off_w1h + NWH * 2;
    const size_t off_bs1 = off_bs0 + 4 * H_ * 4;
    const size_t off_h0 = off_bs1 + 4 * H_ * 4;        // 4 buffers
    const size_t off_h1 = off_h0 + 4 * BH * 2;         // 2 buffers
    const size_t off_flags = off_h1 + 2 * BH * 2;      // 2 x 128 flags x 16B
    const size_t REQ = off_flags + 1024 * 4;

    char* ws = (char*)d_ws;

    if (ws_size >= REQ) {
        f16* xh = (f16*)(ws + off_xh);
        f16* w0i = (f16*)(ws + off_w0i);
        f16* w0h = (f16*)(ws + off_w0h);
        f16* w1i = (f16*)(ws + off_w1i);
        f16* w1h = (f16*)(ws + off_w1h);
        float* bs0 = (float*)(ws + off_bs0);
        float* bs1 = (float*)(ws + off_bs1);
        f16* h0 = (f16*)(ws + off_h0);
        f16* h1 = (f16*)(ws + off_h1);
        int* flags = (int*)(ws + off_flags);

        // zero h0, h1, flags — contiguous tail
        hipMemsetAsync(ws + off_h0, 0, REQ - off_h0, stream);

        dim3 cb(256);
        k_f32_to_f16<<<2048, cb, 0, stream>>>(x, xh, (int)NX);
        k_f32_to_f16<<<2048, cb, 0, stream>>>(Wih0, w0i, (int)NW0I);
        k_f32_to_f16<<<2048, cb, 0, stream>>>(Whh0, w0h, (int)NWH);
        k_f32_to_f16<<<2048, cb, 0, stream>>>(Wih1, w1i, (int)NWH);
        k_f32_to_f16<<<2048, cb, 0, stream>>>(Whh1, w1h, (int)NWH);
        k_bias_sum<<<16, cb, 0, stream>>>(bih0, bhh0, bs0, 4 * H_);
        k_bias_sum<<<16, cb, 0, stream>>>(bih1, bhh1, bs1, 4 * H_);

        lstm_persist4<<<256, 512, 0, stream>>>(xh, w0i, w0h, w1i, w1h, bs0, bs1,
                                               h0, h1, out, flags);
        return;
    }

    // ---------- fp32 fallback ----------
    float* fws = (float*)d_ws;
    float* h0a = fws;
    float* h0b = fws + BH;
    float* c0 = fws + 2 * BH;
    float* h1a = fws + 3 * BH;
    float* h1b = fws + 4 * BH;
    float* c1 = fws + 5 * BH;
    hipMemsetAsync(d_ws, 0, 6 * BH * sizeof(float), stream);

    dim3 grid(H_ / NT, B_ / BM);
    dim3 block(256);
    for (int t = 0; t < T_; ++t) {
        float* h0in = (t & 1) ? h0b : h0a;
        float* h0out = (t & 1) ? h0a : h0b;
        float* h1in = (t & 1) ? h1b : h1a;
        float* h1out = (t & 1) ? h1a : h1b;
        lstm_step<<<grid, block, 0, stream>>>(
            x + (size_t)t * I_, (long)T_ * I_, I_,
            h0in, Wih0, Whh0, bih0, bhh0, c0, h0out, nullptr, 0);
        lstm_step<<<grid, block, 0, stream>>>(
            h0out, (long)H_, H_,
            h1in, Wih1, Whh1, bih1, bhh1, c1, h1out,
            out + (size_t)t * H_, (long)T_ * H_);
    }
}